// Round 14
// baseline (262.098 us; speedup 1.0000x reference)
//
#include <hip/hip_runtime.h>
#include <math.h>

#define E_TOT   640000
#define NN      20000
#define DIM     128
#define EDGE_DIM 16

typedef float f32x4 __attribute__((ext_vector_type(4)));
typedef float f32x2 __attribute__((ext_vector_type(2)));
typedef short s16x8 __attribute__((ext_vector_type(8)));
typedef unsigned u32x4 __attribute__((ext_vector_type(4)));
typedef __bf16 bfx8 __attribute__((ext_vector_type(8)));

__device__ __forceinline__ unsigned short f2bf(float f) {
    unsigned u = __builtin_bit_cast(unsigned, f);
    u += 0x7fffu + ((u >> 16) & 1u);
    return (unsigned short)(u >> 16);
}
__device__ __forceinline__ unsigned cvt_pk_bf16(float lo, float hi) {
    unsigned r;
    asm("v_cvt_pk_bf16_f32 %0, %1, %2" : "=v"(r) : "v"(lo), "v"(hi));
    return r;
}
__device__ __forceinline__ float bf_lo(unsigned u) {
    return __builtin_bit_cast(float, u << 16);
}
__device__ __forceinline__ float bf_hi(unsigned u) {
    return __builtin_bit_cast(float, u & 0xffff0000u);
}
__device__ __forceinline__ f32x2 bf2(unsigned u) {
    f32x2 r; r.x = bf_lo(u); r.y = bf_hi(u); return r;
}
// fast transcendentals (no -ffast-math in harness): v_exp_f32 + v_rcp_f32.
__device__ __forceinline__ float fast_exp2(float x) {
    float r; asm("v_exp_f32 %0, %1" : "=v"(r) : "v"(x)); return r;
}
__device__ __forceinline__ float fast_rcp(float x) {
    float r; asm("v_rcp_f32 %0, %1" : "=v"(r) : "v"(x)); return r;
}
#define LOG2E 1.44269504f
__device__ __forceinline__ float sigmoid_f(float x) {
    return fast_rcp(1.0f + fast_exp2(-LOG2E * x));
}
// pairwise silu: muls/adds emit v_pk_*; exp/rcp stay scalar.
__device__ __forceinline__ f32x2 silu2(f32x2 x) {
    f32x2 nx = x * (-LOG2E);
    f32x2 e; e.x = fast_exp2(nx.x); e.y = fast_exp2(nx.y);
    f32x2 d = e + 1.0f;
    f32x2 rc; rc.x = fast_rcp(d.x); rc.y = fast_rcp(d.y);
    return x * rc;
}

#define MFMA16(a, b, c) __builtin_amdgcn_mfma_f32_16x16x32_bf16( \
    __builtin_bit_cast(bfx8, (a)), __builtin_bit_cast(bfx8, (b)), (c), 0, 0, 0)

// ---------------------------------------------------------------------------
// Weight pack (pair-permuted fragment-major):
// Wp[(sg*128 + f*16 + q)*8 + t] = W[k=sg*8+t][col], col=(f>>1)*32+2q+(f&1).
// ---------------------------------------------------------------------------
__device__ __forceinline__ void pack_w(const float* __restrict__ W,
                                       unsigned short* __restrict__ Wp,
                                       int K, int id) {
    int t   = id & 7;
    int pos = (id >> 3) & 127;
    int sg  = id >> 10;
    int qq = pos & 15, f = pos >> 4;
    int col = (f >> 1) * 32 + 2 * qq + (f & 1);
    int k = sg * 8 + t;
    Wp[id] = (k < K) ? f2bf(W[(size_t)k * DIM + col]) : (unsigned short)0;
}

// ---------------------------------------------------------------------------
// K1: hist (needs only ei; cnts pre-zeroed by tiny memset) + weight packs +
// zero agg. All block-ranges independent.
//  [0,2500): hist; [2500,2900): packs; [2900,5400): zero agg.
// ---------------------------------------------------------------------------
__global__ void hist_pack_kernel(const int* __restrict__ ei,
                                 int* __restrict__ cnts,
                                 const float* __restrict__ Wm1,
                                 const float* __restrict__ Wm2,
                                 const float* __restrict__ Wn1,
                                 const float* __restrict__ Wn2,
                                 unsigned short* __restrict__ W1rp,
                                 unsigned short* __restrict__ W1cp,
                                 unsigned short* __restrict__ W1ep,
                                 unsigned short* __restrict__ W2p,
                                 unsigned short* __restrict__ Wn1p,
                                 unsigned short* __restrict__ Wn2p,
                                 float* __restrict__ agg) {
    const int blk = blockIdx.x;
    const int tid = threadIdx.x;
    if (blk < 2500) {                       // hist
        int e = blk * 256 + tid;
        if (e < E_TOT) atomicAdd(&cnts[ei[e]], 1);
    } else if (blk < 2564) {                // W1rp: rows 0..127 of Wm1
        pack_w(Wm1, W1rp, 128, (blk - 2500) * 256 + tid);
    } else if (blk < 2628) {                // W1cp: rows 128..255
        pack_w(Wm1 + 128 * DIM, W1cp, 128, (blk - 2564) * 256 + tid);
    } else if (blk < 2644) {                // W1ep: rows 256..271, Kp=32
        pack_w(Wm1 + 256 * DIM, W1ep, 16, (blk - 2628) * 256 + tid);
    } else if (blk < 2708) {                // W2p: 128x128
        pack_w(Wm2, W2p, 128, (blk - 2644) * 256 + tid);
    } else if (blk < 2836) {                // Wn1p: 256x128
        pack_w(Wn1, Wn1p, 256, (blk - 2708) * 256 + tid);
    } else if (blk < 2900) {                // Wn2p: 128x128
        pack_w(Wn2, Wn2p, 128, (blk - 2836) * 256 + tid);
    } else {                                // zero agg (640000 f32x4)
        int i = (blk - 2900) * 256 + tid;
        reinterpret_cast<f32x4*>(agg)[i] = (f32x4)0.f;
    }
}

// ---------------------------------------------------------------------------
// K2: scan — counts -> exclusive prefix (in place; becomes scatter cursor)
// ---------------------------------------------------------------------------
__global__ __launch_bounds__(1024) void scan_kernel(int* __restrict__ counts) {
    __shared__ int s[1024];
    const int tid = threadIdx.x;
    const int CH = 20;
    int base = tid * CH;
    int loc[CH];
    int sum = 0;
    #pragma unroll
    for (int i = 0; i < CH; ++i) {
        int idx = base + i;
        loc[i] = (idx < NN) ? counts[idx] : 0;
        sum += loc[i];
    }
    s[tid] = sum;
    __syncthreads();
    for (int off = 1; off < 1024; off <<= 1) {
        int v = (tid >= off) ? s[tid - off] : 0;
        __syncthreads();
        s[tid] += v;
        __syncthreads();
    }
    int run = s[tid] - sum;
    #pragma unroll
    for (int i = 0; i < CH; ++i) {
        int idx = base + i;
        if (idx < NN) counts[idx] = run;
        run += loc[i];
    }
}

// ---------------------------------------------------------------------------
// K3: prep_h + scatter + proj fused (all independent after scan):
//  [0,2500): h -> h_bf; [2500,5000): counting-sort scatter;
//  [5000,5313): P1r/P1c projections reading RAW f32 h (in-register cvt).
// !SORTED: [0,2500) prep_h; [2500,2813) proj.
// ---------------------------------------------------------------------------
template<bool SORTED>
__global__ __launch_bounds__(256) void prep_scatter_proj_kernel(
    const float* __restrict__ h,
    unsigned short* __restrict__ h_bf,
    const int* __restrict__ ei, int* __restrict__ cursor,
    int* __restrict__ eidS, unsigned short* __restrict__ rowS,
    const unsigned short* __restrict__ W1rp,
    const unsigned short* __restrict__ W1cp,
    unsigned* __restrict__ P1r, unsigned* __restrict__ P1c)
{
    const int blk = blockIdx.x;
    const int tid = threadIdx.x;

    if (blk < 2500) {                       // h -> bf16
        int i = blk * 256 + tid;
        float4 v = reinterpret_cast<const float4*>(h)[i];
        unsigned short* d = h_bf + i * 4;
        d[0] = f2bf(v.x); d[1] = f2bf(v.y); d[2] = f2bf(v.z); d[3] = f2bf(v.w);
        return;
    }
    if (SORTED && blk < 5000) {             // scatter
        int e = (blk - 2500) * 256 + tid;
        if (e < E_TOT) {
            int r = ei[e];
            int p = atomicAdd(&cursor[r], 1);
            eidS[p] = e;
            rowS[p] = (unsigned short)r;
        }
        return;
    }

    // proj (reads raw f32 h; independent of the prep_h blocks)
    const int pblk = SORTED ? (blk - 5000) : (blk - 2500);
    const int wv   = tid >> 6;
    const int lane = tid & 63;
    const int q    = lane & 15;
    const int g    = lane >> 4;
    const int n0w  = pblk * 64 + wv * 16;
    const int nq   = n0w + q;
    const int nqc  = (nq < NN) ? nq : (NN - 1);

    s16x8 av[4];
    #pragma unroll
    for (int s = 0; s < 4; ++s) {
        const float4* ph = reinterpret_cast<const float4*>(
            h + (size_t)nqc * DIM + s * 32 + g * 8);
        float4 u = ph[0], v = ph[1];
        u32x4 pk;
        pk[0] = cvt_pk_bf16(u.x, u.y); pk[1] = cvt_pk_bf16(u.z, u.w);
        pk[2] = cvt_pk_bf16(v.x, v.y); pk[3] = cvt_pk_bf16(v.z, v.w);
        av[s] = __builtin_bit_cast(s16x8, pk);
    }

    #pragma unroll
    for (int T = 0; T < 2; ++T) {
        const unsigned short* Wp = T ? W1cp : W1rp;
        unsigned* P = T ? P1c : P1r;
        f32x4 acc[8];
        #pragma unroll
        for (int f = 0; f < 8; ++f) acc[f] = (f32x4)0.f;
        #pragma unroll
        for (int s = 0; s < 4; ++s)
            #pragma unroll
            for (int f = 0; f < 8; ++f) {
                s16x8 b = *reinterpret_cast<const s16x8*>(
                    Wp + ((s * 4 + g) * DIM + f * 16 + q) * 8);
                acc[f] = MFMA16(av[s], b, acc[f]);
            }
        #pragma unroll
        for (int r = 0; r < 4; ++r) {
            int n = n0w + g * 4 + r;
            if (n < NN) {
                u32x4 o;
                #pragma unroll
                for (int a = 0; a < 4; ++a)
                    o[a] = cvt_pk_bf16(acc[2 * a][r], acc[2 * a + 1][r]);
                *reinterpret_cast<u32x4*>(P + (size_t)n * 64 + q * 4) = o;
            }
        }
    }
}

// ---------------------------------------------------------------------------
// Edge kernel (r13 structure; NEW: all 32 P-gathers issued upfront — LDS
// caps occupancy at 2 waves/SIMD so VGPR headroom to ~256 is free).
// ---------------------------------------------------------------------------
template<bool SORTED>
__global__ __launch_bounds__(256, 2) void edge_kernel(
    const unsigned* __restrict__ P1r,
    const unsigned* __restrict__ P1c,
    const int* __restrict__ ei,
    const int* __restrict__ eidS,
    const unsigned short* __restrict__ rowS,
    const float* __restrict__ ea,
    const float* __restrict__ emask,
    const unsigned short* __restrict__ W1ep,  // 32x128 packed (pair-permuted)
    const float* __restrict__ bm1,
    const unsigned short* __restrict__ W2p,   // 128x128 packed (pair-permuted)
    const float* __restrict__ bm2,
    const float* __restrict__ Wa, const float* __restrict__ ba,
    float* __restrict__ agg)
{
    __shared__ __align__(16) unsigned char s_u[4][16384];  // wave-private

    const int tid  = threadIdx.x;
    const int wv   = tid >> 6;
    const int lane = tid & 63;
    const int q    = lane & 15;
    const int g    = lane >> 4;

    // bijective XCD swizzle: contiguous sorted-edge tiles share one L2.
    const int nwg = gridDim.x;
    const int xcd = blockIdx.x & 7;
    const int loc = blockIdx.x >> 3;
    const int qq  = nwg >> 3, rr = nwg & 7;
    const int tile = (xcd < rr) ? (xcd * (qq + 1) + loc)
                                : (rr * (qq + 1) + (xcd - rr) * qq + loc);
    const int e0w = tile * 256 + wv * 64;

    // per-lane meta: lane l holds edge (e0w + l)
    const int   eidl = SORTED ? eidS[e0w + lane] : (e0w + lane);
    const int   rowl = SORTED ? (int)rowS[e0w + lane] : ei[eidl];
    const int   coll = ei[E_TOT + eidl];
    const float mskl = emask[eidl];

    const u32x4* P1r4 = reinterpret_cast<const u32x4*>(P1r);
    const u32x4* P1c4 = reinterpret_cast<const u32x4*>(P1c);

    // ALL P-gathers upfront (32 x u32x4 per lane — independent, in flight)
    u32x4 pr[4][4], pc[4][4];
    #pragma unroll
    for (int mi = 0; mi < 4; ++mi)
        #pragma unroll
        for (int r = 0; r < 4; ++r) {
            int e = mi * 16 + g * 4 + r;
            pr[mi][r] = P1r4[(size_t)__shfl(rowl, e) * 16 + q];
            pc[mi][r] = P1c4[(size_t)__shfl(coll, e) * 16 + q];
        }

    // ea A-fragments for all mi (lane (q,g) covers edge mi*16+q, k=g*8..+8)
    s16x8 eav[4];
    #pragma unroll
    for (int mi = 0; mi < 4; ++mi) {
        int eid = __shfl(eidl, mi * 16 + q);
        eav[mi] = (s16x8)0;
        if (g < 2) {
            const float4* pe = reinterpret_cast<const float4*>(
                ea + (size_t)eid * EDGE_DIM + g * 8);
            float4 u = pe[0], v = pe[1];
            u32x4 pk;
            pk[0] = cvt_pk_bf16(u.x, u.y); pk[1] = cvt_pk_bf16(u.z, u.w);
            pk[2] = cvt_pk_bf16(v.x, v.y); pk[3] = cvt_pk_bf16(v.z, v.w);
            eav[mi] = __builtin_bit_cast(s16x8, pk);
        }
    }

    // W1e B-fragments (Kp=32 -> single s-step, sg=g)
    s16x8 w1e[8];
    #pragma unroll
    for (int f = 0; f < 8; ++f)
        w1e[f] = *reinterpret_cast<const s16x8*>(
            W1ep + ((size_t)g * DIM + f * 16 + q) * 8);

    f32x2 b1v[4];
    #pragma unroll
    for (int a = 0; a < 4; ++a)
        b1v[a] = *reinterpret_cast<const f32x2*>(bm1 + a * 32 + 2 * q);

    unsigned char* sw = s_u[wv];

    // ---------------- layer 1 (factored), per-mi ----------------
    #pragma unroll
    for (int mi = 0; mi < 4; ++mi) {
        f32x4 a1[8];
        #pragma unroll
        for (int f = 0; f < 8; ++f) a1[f] = (f32x4)0.f;
        #pragma unroll
        for (int f = 0; f < 8; ++f) a1[f] = MFMA16(eav[mi], w1e[f], a1[f]);

        #pragma unroll
        for (int r = 0; r < 4; ++r) {
            int e = mi * 16 + g * 4 + r;
            unsigned sx = (unsigned)((e & 7) << 4);
            #pragma unroll
            for (int a = 0; a < 4; ++a) {
                f32x2 t; t.x = a1[2 * a][r]; t.y = a1[2 * a + 1][r];
                t = t + bf2(pr[mi][r][a]) + bf2(pc[mi][r][a]) + b1v[a];
                f32x2 s = silu2(t);
                *reinterpret_cast<unsigned*>(
                    sw + e * 256 + ((a * 64 + q * 4) ^ sx)) = cvt_pk_bf16(s.x, s.y);
            }
        }
    }
    // same-wave LDS RAW -> compiler lgkmcnt; no barrier

    // ---------------- layer 2: k=0..127 ----------------
    f32x4 acc2[4][8];
    #pragma unroll
    for (int mi = 0; mi < 4; ++mi)
        #pragma unroll
        for (int f = 0; f < 8; ++f) acc2[mi][f] = (f32x4)0.f;

    #pragma unroll
    for (int s = 0; s < 4; ++s) {
        s16x8 bf[8];
        #pragma unroll
        for (int f = 0; f < 8; ++f)
            bf[f] = *reinterpret_cast<const s16x8*>(
                W2p + ((s * 4 + g) * DIM + f * 16 + q) * 8);
        s16x8 av[4];
        #pragma unroll
        for (int mi = 0; mi < 4; ++mi) {
            int e = mi * 16 + q;
            av[mi] = *reinterpret_cast<const s16x8*>(
                sw + e * 256 + ((s * 64 + g * 16) ^ ((q & 7) << 4)));
        }
        #pragma unroll
        for (int mi = 0; mi < 4; ++mi)
            #pragma unroll
            for (int f = 0; f < 8; ++f) acc2[mi][f] = MFMA16(av[mi], bf[f], acc2[mi][f]);
    }

    // bias + silu (pairwise); attention dot via pk-fma; sigmoid*mask; pack msgs
    unsigned* smsg = reinterpret_cast<unsigned*>(sw);
    {
        f32x2 b2v[4], wav[4];
        #pragma unroll
        for (int a = 0; a < 4; ++a) {
            b2v[a] = *reinterpret_cast<const f32x2*>(bm2 + a * 32 + 2 * q);
            wav[a] = *reinterpret_cast<const f32x2*>(Wa  + a * 32 + 2 * q);
        }
        const float ba0 = ba[0];
        #pragma unroll
        for (int mi = 0; mi < 4; ++mi)
            #pragma unroll
            for (int r = 0; r < 4; ++r) {
                f32x2 pd = (f32x2)0.f;
                f32x2 vv[4];
                #pragma unroll
                for (int a = 0; a < 4; ++a) {
                    f32x2 t; t.x = acc2[mi][2 * a][r]; t.y = acc2[mi][2 * a + 1][r];
                    t = t + b2v[a];
                    vv[a] = silu2(t);
                    pd = pd + vv[a] * wav[a];
                }
                float p = pd.x + pd.y;
                p += __shfl_xor(p, 1);
                p += __shfl_xor(p, 2);
                p += __shfl_xor(p, 4);
                p += __shfl_xor(p, 8);
                int e = mi * 16 + g * 4 + r;
                float mk = __shfl(mskl, e);
                float sc = sigmoid_f(p + ba0) * mk;
                unsigned sx = ((unsigned)(e & 4)) << 2;
                #pragma unroll
                for (int a = 0; a < 4; ++a) {
                    f32x2 m = vv[a] * sc;
                    smsg[e * 64 + ((a * 16 + q) ^ sx)] = cvt_pk_bf16(m.x, m.y);
                }
            }
    }

    // segmented run-reduction over the wave's 64 sorted edges (pk accumulate).
    {
        const int c = lane;
        f32x2 s = (f32x2)0.f;
        int prow = __builtin_amdgcn_readlane(rowl, 0);
        for (int jb = 0; jb < 64; jb += 8) {
            unsigned v[8];
            #pragma unroll
            for (int k = 0; k < 8; ++k)
                v[k] = smsg[(jb + k) * 64 + (c ^ (((jb + k) & 4) << 2))];
            #pragma unroll
            for (int k = 0; k < 8; ++k) {
                int rj = __builtin_amdgcn_readlane(rowl, jb + k);
                if (rj != prow) {                    // wave-uniform branch
                    float* dst = agg + (size_t)prow * DIM + (c >> 4) * 32 + 2 * (c & 15);
                    atomicAdd(dst, s.x);
                    atomicAdd(dst + 1, s.y);
                    s = (f32x2)0.f; prow = rj;
                }
                s = s + bf2(v[k]);
            }
        }
        float* dst = agg + (size_t)prow * DIM + (c >> 4) * 32 + 2 * (c & 15);
        atomicAdd(dst, s.x);
        atomicAdd(dst + 1, s.y);
    }
}

// ---------------------------------------------------------------------------
// Node kernel v2: 2x occupancy via column-split. Block = 32 nodes; wave
// (grp,half) owns 16 nodes x 64 cols (f_global = half*4 + f). One barrier
// between layers (hidden row spans both halves). Grid 625 (~2.4 blocks/CU
// vs 1.2 before). Hoisted loads + pairwise f32x2 epilogues.
// ---------------------------------------------------------------------------
__global__ __launch_bounds__(256, 4) void node_kernel(
    const unsigned short* __restrict__ h_bf,
    const float* __restrict__ agg,
    const float* __restrict__ h,
    const float* __restrict__ flags,
    const unsigned short* __restrict__ Wn1p,
    const float* __restrict__ bn1,
    const unsigned short* __restrict__ Wn2p,
    const float* __restrict__ bn2,
    float* __restrict__ out)
{
    __shared__ __align__(16) unsigned char s_u[2][4352];

    const int tid  = threadIdx.x;
    const int wv   = tid >> 6;
    const int lane = tid & 63;
    const int q    = lane & 15;
    const int g    = lane >> 4;
    const int grp  = wv >> 1;
    const int half = wv & 1;
    const int n0w  = blockIdx.x * 32 + grp * 16;

    const int nq  = n0w + q;
    const int nqc = (nq < NN) ? nq : (NN - 1);

    // hoist ALL global loads: agg (8 x float4) + h_bf (4 x 16B)
    float4 au[4], avv[4];
    #pragma unroll
    for (int s = 0; s < 4; ++s) {
        const float4* pa = reinterpret_cast<const float4*>(
            agg + (size_t)nqc * DIM + s * 32 + g * 8);
        au[s] = pa[0]; avv[s] = pa[1];
    }
    s16x8 ah[4];
    #pragma unroll
    for (int s = 0; s < 4; ++s)
        ah[s] = *reinterpret_cast<const s16x8*>(
            h_bf + (size_t)nqc * DIM + s * 32 + g * 8);

    f32x4 acc[4];
    #pragma unroll
    for (int f = 0; f < 4; ++f) acc[f] = (f32x4)0.f;

    #pragma unroll
    for (int s = 0; s < 4; ++s) {
        #pragma unroll
        for (int f = 0; f < 4; ++f) {
            s16x8 b = *reinterpret_cast<const s16x8*>(
                Wn1p + ((s * 4 + g) * DIM + (half * 4 + f) * 16 + q) * 8);
            acc[f] = MFMA16(ah[s], b, acc[f]);
        }
    }
    #pragma unroll
    for (int s = 4; s < 8; ++s) {
        float4 u = au[s - 4], v = avv[s - 4];
        u32x4 pk;
        pk[0] = cvt_pk_bf16(u.x, u.y); pk[1] = cvt_pk_bf16(u.z, u.w);
        pk[2] = cvt_pk_bf16(v.x, v.y); pk[3] = cvt_pk_bf16(v.z, v.w);
        s16x8 a = __builtin_bit_cast(s16x8, pk);
        #pragma unroll
        for (int f = 0; f < 4; ++f) {
            s16x8 b = *reinterpret_cast<const s16x8*>(
                Wn1p + ((s * 4 + g) * DIM + (half * 4 + f) * 16 + q) * 8);
            acc[f] = MFMA16(a, b, acc[f]);
        }
    }

    unsigned char* sg_ = s_u[grp];
    {
        #pragma unroll
        for (int a = 0; a < 2; ++a) {
            int aa = half * 2 + a;
            f32x2 bp = *reinterpret_cast<const f32x2*>(bn1 + aa * 32 + 2 * q);
            #pragma unroll
            for (int r = 0; r < 4; ++r) {
                f32x2 t; t.x = acc[2 * a][r]; t.y = acc[2 * a + 1][r];
                f32x2 s = silu2(t + bp);
                *reinterpret_cast<unsigned*>(
                    sg_ + (g * 4 + r) * 272 + aa * 64 + 4 * q) = cvt_pk_bf16(s.x, s.y);
            }
        }
    }
    __syncthreads();   // hidden row spans both column-half waves

    f32x4 acc2[4];
    #pragma unroll
    for (int f = 0; f < 4; ++f) acc2[f] = (f32x4)0.f;

    #pragma unroll
    for (int s = 0; s < 4; ++s) {
        s16x8 a = *reinterpret_cast<const s16x8*>(sg_ + q * 272 + s * 64 + g * 16);
        #pragma unroll
        for (int f = 0; f < 4; ++f) {
            s16x8 b = *reinterpret_cast<const s16x8*>(
                Wn2p + ((s * 4 + g) * DIM + (half * 4 + f) * 16 + q) * 8);
            acc2[f] = MFMA16(a, b, acc2[f]);
        }
    }

    {
        #pragma unroll
        for (int r = 0; r < 4; ++r) {
            int n = n0w + 4 * g + r;
            if (n < NN) {
                float fl = flags[n];
                #pragma unroll
                for (int a = 0; a < 2; ++a) {
                    int aa = half * 2 + a;
                    f32x2 b2 = *reinterpret_cast<const f32x2*>(bn2 + aa * 32 + 2 * q);
                    size_t b = (size_t)n * DIM + aa * 32 + 2 * q;
                    f32x2 hv = *reinterpret_cast<const f32x2*>(h + b);
                    f32x2 t; t.x = acc2[2 * a][r]; t.y = acc2[2 * a + 1][r];
                    f32x2 o = (hv + t + b2) * fl;
                    *reinterpret_cast<f32x2*>(out + b) = o;
                }
            }
        }
    }
}

extern "C" void kernel_launch(void* const* d_in, const int* in_sizes, int n_in,
                              void* d_out, int out_size, void* d_ws, size_t ws_size,
                              hipStream_t stream) {
    const float* h     = (const float*)d_in[0];
    const int*   ei    = (const int*)  d_in[1];
    const float* ea    = (const float*)d_in[2];
    const float* flags = (const float*)d_in[3];
    const float* emask = (const float*)d_in[4];
    const float* Wm1   = (const float*)d_in[5];
    const float* bm1   = (const float*)d_in[6];
    const float* Wm2   = (const float*)d_in[7];
    const float* bm2   = (const float*)d_in[8];
    const float* Wa    = (const float*)d_in[9];
    const float* ba    = (const float*)d_in[10];
    const float* Wn1   = (const float*)d_in[11];
    const float* bn1   = (const float*)d_in[12];
    const float* Wn2   = (const float*)d_in[13];
    const float* bn2   = (const float*)d_in[14];
    float* out = (float*)d_out;

    char* ws = (char*)d_ws;
    float*          agg   = (float*)         (ws);                 // 10,240,000
    unsigned short* h_bf  = (unsigned short*)(ws + 10240000);      //  5,120,000
    unsigned short* W1rp  = (unsigned short*)(ws + 15360000);      //     32,768
    unsigned short* W1cp  = (unsigned short*)(ws + 15392768);      //     32,768
    unsigned short* W1ep  = (unsigned short*)(ws + 15425536);      //      8,192
    unsigned short* W2p   = (unsigned short*)(ws + 15433728);      //     32,768
    unsigned short* Wn1p  = (unsigned short*)(ws + 15466496);      //     65,536
    unsigned short* Wn2p  = (unsigned short*)(ws + 15532032);      //     32,768
    int*            cnts  = (int*)           (ws + 15564800);      //     80,000
    int*            eidS  = (int*)           (ws + 15644800);      //  2,560,000
    unsigned short* rowS  = (unsigned short*)(ws + 18204800);      //  1,280,000
    unsigned*       P1r   = (unsigned*)      (ws + 19484800);      //  5,120,000
    unsigned*       P1c   = (unsigned*)      (ws + 24604800);      //  5,120,000
    const size_t WS_NEED = 29724800;

    const bool sorted = (ws_size >= WS_NEED);

    if (sorted) {
        hipMemsetAsync(cnts, 0, NN * sizeof(int), stream);   // tiny (80 KB)
        hist_pack_kernel<<<5400, 256, 0, stream>>>(
            ei, cnts, Wm1, Wm2, Wn1, Wn2,
            W1rp, W1cp, W1ep, W2p, Wn1p, Wn2p, agg);
        scan_kernel<<<1, 1024, 0, stream>>>(cnts);
        prep_scatter_proj_kernel<true><<<5313, 256, 0, stream>>>(
            h, h_bf, ei, cnts, eidS, rowS, W1rp, W1cp, P1r, P1c);
        edge_kernel<true><<<E_TOT / 256, 256, 0, stream>>>(
            P1r, P1c, ei, eidS, rowS, ea, emask, W1ep, bm1, W2p, bm2, Wa, ba, agg);
    } else {
        hipMemsetAsync(cnts, 0, NN * sizeof(int), stream);
        hist_pack_kernel<<<5400, 256, 0, stream>>>(
            ei, cnts, Wm1, Wm2, Wn1, Wn2,
            W1rp, W1cp, W1ep, W2p, Wn1p, Wn2p, agg);
        prep_scatter_proj_kernel<false><<<2813, 256, 0, stream>>>(
            h, h_bf, ei, cnts, eidS, rowS, W1rp, W1cp, P1r, P1c);
        edge_kernel<false><<<E_TOT / 256, 256, 0, stream>>>(
            P1r, P1c, ei, eidS, rowS, ea, emask, W1ep, bm1, W2p, bm2, Wa, ba, agg);
    }

    node_kernel<<<(NN + 31) / 32, 256, 0, stream>>>(h_bf, agg, h, flags,
                                                    Wn1p, bn1, Wn2p, bn2, out);
}

// Round 15
// 227.707 us; speedup vs baseline: 1.1510x; 1.1510x over previous
//
#include <hip/hip_runtime.h>
#include <math.h>

#define E_TOT   640000
#define NN      20000
#define DIM     128
#define EDGE_DIM 16

typedef float f32x4 __attribute__((ext_vector_type(4)));
typedef float f32x2 __attribute__((ext_vector_type(2)));
typedef short s16x8 __attribute__((ext_vector_type(8)));
typedef unsigned u32x4 __attribute__((ext_vector_type(4)));
typedef __bf16 bfx8 __attribute__((ext_vector_type(8)));

__device__ __forceinline__ unsigned short f2bf(float f) {
    unsigned u = __builtin_bit_cast(unsigned, f);
    u += 0x7fffu + ((u >> 16) & 1u);
    return (unsigned short)(u >> 16);
}
__device__ __forceinline__ unsigned cvt_pk_bf16(float lo, float hi) {
    unsigned r;
    asm("v_cvt_pk_bf16_f32 %0, %1, %2" : "=v"(r) : "v"(lo), "v"(hi));
    return r;
}
__device__ __forceinline__ float bf_lo(unsigned u) {
    return __builtin_bit_cast(float, u << 16);
}
__device__ __forceinline__ float bf_hi(unsigned u) {
    return __builtin_bit_cast(float, u & 0xffff0000u);
}
__device__ __forceinline__ f32x2 bf2(unsigned u) {
    f32x2 r; r.x = bf_lo(u); r.y = bf_hi(u); return r;
}
// fast transcendentals (no -ffast-math in harness): v_exp_f32 + v_rcp_f32.
__device__ __forceinline__ float fast_exp2(float x) {
    float r; asm("v_exp_f32 %0, %1" : "=v"(r) : "v"(x)); return r;
}
__device__ __forceinline__ float fast_rcp(float x) {
    float r; asm("v_rcp_f32 %0, %1" : "=v"(r) : "v"(x)); return r;
}
#define LOG2E 1.44269504f
__device__ __forceinline__ float silu_f(float x) {
    return x * fast_rcp(1.0f + fast_exp2(-LOG2E * x));
}
__device__ __forceinline__ float sigmoid_f(float x) {
    return fast_rcp(1.0f + fast_exp2(-LOG2E * x));
}
// pairwise silu on a column pair: muls/adds become v_pk_*; exp/rcp stay scalar.
__device__ __forceinline__ f32x2 silu2(f32x2 x) {
    f32x2 nx = x * (-LOG2E);
    f32x2 e; e.x = fast_exp2(nx.x); e.y = fast_exp2(nx.y);
    f32x2 d = e + 1.0f;
    f32x2 rc; rc.x = fast_rcp(d.x); rc.y = fast_rcp(d.y);
    return x * rc;
}

#define MFMA16(a, b, c) __builtin_amdgcn_mfma_f32_16x16x32_bf16( \
    __builtin_bit_cast(bfx8, (a)), __builtin_bit_cast(bfx8, (b)), (c), 0, 0, 0)

// ---------------------------------------------------------------------------
// mega-prep (r10 structure): h->bf16, weight packs (pair-permuted
// fragment-major), zero agg and cnts in-kernel. Pack:
// Wp[(sg*128 + f*16 + q)*8 + t] = W[k=sg*8+t][col], col=(f>>1)*32+2q+(f&1).
// ---------------------------------------------------------------------------
__device__ __forceinline__ void pack_w(const float* __restrict__ W,
                                       unsigned short* __restrict__ Wp,
                                       int K, int id) {
    int t   = id & 7;
    int pos = (id >> 3) & 127;
    int sg  = id >> 10;
    int qq = pos & 15, f = pos >> 4;
    int col = (f >> 1) * 32 + 2 * qq + (f & 1);
    int k = sg * 8 + t;
    Wp[id] = (k < K) ? f2bf(W[(size_t)k * DIM + col]) : (unsigned short)0;
}

__global__ void prep_all_kernel(const float* __restrict__ h,
                                unsigned short* __restrict__ h_bf,
                                const float* __restrict__ Wm1,
                                const float* __restrict__ Wm2,
                                const float* __restrict__ Wn1,
                                const float* __restrict__ Wn2,
                                unsigned short* __restrict__ W1rp,
                                unsigned short* __restrict__ W1cp,
                                unsigned short* __restrict__ W1ep,
                                unsigned short* __restrict__ W2p,
                                unsigned short* __restrict__ Wn1p,
                                unsigned short* __restrict__ Wn2p,
                                float* __restrict__ agg,
                                int* __restrict__ cnts) {
    const int blk = blockIdx.x;
    const int tid = threadIdx.x;
    if (blk < 2500) {                       // h -> bf16 (640000 f32x4)
        int i = blk * 256 + tid;
        float4 v = reinterpret_cast<const float4*>(h)[i];
        unsigned short* d = h_bf + i * 4;
        d[0] = f2bf(v.x); d[1] = f2bf(v.y); d[2] = f2bf(v.z); d[3] = f2bf(v.w);
    } else if (blk < 2564) {                // W1rp: rows 0..127 of Wm1
        pack_w(Wm1, W1rp, 128, (blk - 2500) * 256 + tid);
    } else if (blk < 2628) {                // W1cp: rows 128..255
        pack_w(Wm1 + 128 * DIM, W1cp, 128, (blk - 2564) * 256 + tid);
    } else if (blk < 2644) {                // W1ep: rows 256..271, Kp=32
        pack_w(Wm1 + 256 * DIM, W1ep, 16, (blk - 2628) * 256 + tid);
    } else if (blk < 2708) {                // W2p: 128x128
        pack_w(Wm2, W2p, 128, (blk - 2644) * 256 + tid);
    } else if (blk < 2836) {                // Wn1p: 256x128
        pack_w(Wn1, Wn1p, 256, (blk - 2708) * 256 + tid);
    } else if (blk < 2900) {                // Wn2p: 128x128
        pack_w(Wn2, Wn2p, 128, (blk - 2836) * 256 + tid);
    } else if (blk < 5400) {                // zero agg (640000 f32x4)
        int i = (blk - 2900) * 256 + tid;
        reinterpret_cast<f32x4*>(agg)[i] = (f32x4)0.f;
    } else {                                // zero cnts (20000 ints)
        int i = (blk - 5400) * 256 + tid;
        if (i < NN) cnts[i] = 0;
    }
}

// ---------------------------------------------------------------------------
// hist + proj fused (independent after prep; complementary resource use):
//  blocks [0,2500): edge-row histogram;
//  blocks [2500,2813): P1r/P1c projections (P[n*64+q*4+a] bf16-pairs).
// !SORTED fallback: proj only.
// ---------------------------------------------------------------------------
template<bool SORTED>
__global__ __launch_bounds__(256) void hist_proj_kernel(
    const int* __restrict__ ei, int* __restrict__ cnts,
    const unsigned short* __restrict__ h_bf,
    const unsigned short* __restrict__ W1rp,
    const unsigned short* __restrict__ W1cp,
    unsigned* __restrict__ P1r, unsigned* __restrict__ P1c)
{
    const int blk = blockIdx.x;
    const int tid = threadIdx.x;

    if (SORTED && blk < 2500) {             // hist
        int e = blk * 256 + tid;
        if (e < E_TOT) atomicAdd(&cnts[ei[e]], 1);
        return;
    }

    // proj
    const int pblk = SORTED ? (blk - 2500) : blk;
    const int wv   = tid >> 6;
    const int lane = tid & 63;
    const int q    = lane & 15;
    const int g    = lane >> 4;
    const int n0w  = pblk * 64 + wv * 16;
    const int nq   = n0w + q;
    const int nqc  = (nq < NN) ? nq : (NN - 1);

    s16x8 av[4];
    #pragma unroll
    for (int s = 0; s < 4; ++s)
        av[s] = *reinterpret_cast<const s16x8*>(
            h_bf + (size_t)nqc * DIM + s * 32 + g * 8);

    #pragma unroll
    for (int T = 0; T < 2; ++T) {
        const unsigned short* Wp = T ? W1cp : W1rp;
        unsigned* P = T ? P1c : P1r;
        f32x4 acc[8];
        #pragma unroll
        for (int f = 0; f < 8; ++f) acc[f] = (f32x4)0.f;
        #pragma unroll
        for (int s = 0; s < 4; ++s)
            #pragma unroll
            for (int f = 0; f < 8; ++f) {
                s16x8 b = *reinterpret_cast<const s16x8*>(
                    Wp + ((s * 4 + g) * DIM + f * 16 + q) * 8);
                acc[f] = MFMA16(av[s], b, acc[f]);
            }
        #pragma unroll
        for (int r = 0; r < 4; ++r) {
            int n = n0w + g * 4 + r;
            if (n < NN) {
                u32x4 o;
                #pragma unroll
                for (int a = 0; a < 4; ++a)
                    o[a] = cvt_pk_bf16(acc[2 * a][r], acc[2 * a + 1][r]);
                *reinterpret_cast<u32x4*>(P + (size_t)n * 64 + q * 4) = o;
            }
        }
    }
}

// ---------------------------------------------------------------------------
// scan: counts -> exclusive prefix (in place; becomes scatter cursor)
// ---------------------------------------------------------------------------
__global__ __launch_bounds__(1024) void scan_kernel(int* __restrict__ counts) {
    __shared__ int s[1024];
    const int tid = threadIdx.x;
    const int CH = 20;
    int base = tid * CH;
    int loc[CH];
    int sum = 0;
    #pragma unroll
    for (int i = 0; i < CH; ++i) {
        int idx = base + i;
        loc[i] = (idx < NN) ? counts[idx] : 0;
        sum += loc[i];
    }
    s[tid] = sum;
    __syncthreads();
    for (int off = 1; off < 1024; off <<= 1) {
        int v = (tid >= off) ? s[tid - off] : 0;
        __syncthreads();
        s[tid] += v;
        __syncthreads();
    }
    int run = s[tid] - sum;
    #pragma unroll
    for (int i = 0; i < CH; ++i) {
        int idx = base + i;
        if (idx < NN) counts[idx] = run;
        run += loc[i];
    }
}

__global__ void scatter_kernel(const int* __restrict__ ei, int* __restrict__ cursor,
                               int* __restrict__ eidS, unsigned short* __restrict__ rowS) {
    int e = blockIdx.x * blockDim.x + threadIdx.x;
    if (e < E_TOT) {
        int r = ei[e];
        int p = atomicAdd(&cursor[r], 1);
        eidS[p] = e;
        rowS[p] = (unsigned short)r;
    }
}

// ---------------------------------------------------------------------------
// Edge kernel (r12 structure, epilogues rewritten on f32x2 so the pairable
// adds/muls emit v_pk_add_f32 / v_pk_mul_f32 / v_pk_fma_f32; transcendentals
// remain scalar — they have no packed form).
// ---------------------------------------------------------------------------
template<bool SORTED>
__global__ __launch_bounds__(256, 2) void edge_kernel(
    const unsigned* __restrict__ P1r,
    const unsigned* __restrict__ P1c,
    const int* __restrict__ ei,
    const int* __restrict__ eidS,
    const unsigned short* __restrict__ rowS,
    const float* __restrict__ ea,
    const float* __restrict__ emask,
    const unsigned short* __restrict__ W1ep,  // 32x128 packed (pair-permuted)
    const float* __restrict__ bm1,
    const unsigned short* __restrict__ W2p,   // 128x128 packed (pair-permuted)
    const float* __restrict__ bm2,
    const float* __restrict__ Wa, const float* __restrict__ ba,
    float* __restrict__ agg)
{
    __shared__ __align__(16) unsigned char s_u[4][16384];  // wave-private

    const int tid  = threadIdx.x;
    const int wv   = tid >> 6;
    const int lane = tid & 63;
    const int q    = lane & 15;
    const int g    = lane >> 4;

    // bijective XCD swizzle: contiguous sorted-edge tiles share one L2.
    const int nwg = gridDim.x;
    const int xcd = blockIdx.x & 7;
    const int loc = blockIdx.x >> 3;
    const int qq  = nwg >> 3, rr = nwg & 7;
    const int tile = (xcd < rr) ? (xcd * (qq + 1) + loc)
                                : (rr * (qq + 1) + (xcd - rr) * qq + loc);
    const int e0w = tile * 256 + wv * 64;

    // per-lane meta: lane l holds edge (e0w + l)
    const int   eidl = SORTED ? eidS[e0w + lane] : (e0w + lane);
    const int   rowl = SORTED ? (int)rowS[e0w + lane] : ei[eidl];
    const int   coll = ei[E_TOT + eidl];
    const float mskl = emask[eidl];

    const u32x4* P1r4 = reinterpret_cast<const u32x4*>(P1r);
    const u32x4* P1c4 = reinterpret_cast<const u32x4*>(P1c);

    // ea A-fragments for all mi (lane (q,g) covers edge mi*16+q, k=g*8..+8)
    s16x8 eav[4];
    #pragma unroll
    for (int mi = 0; mi < 4; ++mi) {
        int eid = __shfl(eidl, mi * 16 + q);
        eav[mi] = (s16x8)0;
        if (g < 2) {
            const float4* pe = reinterpret_cast<const float4*>(
                ea + (size_t)eid * EDGE_DIM + g * 8);
            float4 u = pe[0], v = pe[1];
            u32x4 pk;
            pk[0] = cvt_pk_bf16(u.x, u.y); pk[1] = cvt_pk_bf16(u.z, u.w);
            pk[2] = cvt_pk_bf16(v.x, v.y); pk[3] = cvt_pk_bf16(v.z, v.w);
            eav[mi] = __builtin_bit_cast(s16x8, pk);
        }
    }

    // W1e B-fragments (Kp=32 -> single s-step, sg=g)
    s16x8 w1e[8];
    #pragma unroll
    for (int f = 0; f < 8; ++f)
        w1e[f] = *reinterpret_cast<const s16x8*>(
            W1ep + ((size_t)g * DIM + f * 16 + q) * 8);

    f32x2 b1v[4];
    #pragma unroll
    for (int a = 0; a < 4; ++a)
        b1v[a] = *reinterpret_cast<const f32x2*>(bm1 + a * 32 + 2 * q);

    unsigned char* sw = s_u[wv];

    // prefetch P for mi=0 (epilogue lane (q,g) handles edges mi*16+g*4+r)
    u32x4 pr[4], pc[4];
    #pragma unroll
    for (int r = 0; r < 4; ++r) {
        int e = g * 4 + r;
        pr[r] = P1r4[(size_t)__shfl(rowl, e) * 16 + q];
        pc[r] = P1c4[(size_t)__shfl(coll, e) * 16 + q];
    }

    // ---------------- layer 1 (factored), per-mi ----------------
    #pragma unroll
    for (int mi = 0; mi < 4; ++mi) {
        f32x4 a1[8];
        #pragma unroll
        for (int f = 0; f < 8; ++f) a1[f] = (f32x4)0.f;
        #pragma unroll
        for (int f = 0; f < 8; ++f) a1[f] = MFMA16(eav[mi], w1e[f], a1[f]);

        // prefetch next mi's P-rows while this epilogue runs
        u32x4 prn[4], pcn[4];
        if (mi < 3) {
            #pragma unroll
            for (int r = 0; r < 4; ++r) {
                int e = (mi + 1) * 16 + g * 4 + r;
                prn[r] = P1r4[(size_t)__shfl(rowl, e) * 16 + q];
                pcn[r] = P1c4[(size_t)__shfl(coll, e) * 16 + q];
            }
        }

        #pragma unroll
        for (int r = 0; r < 4; ++r) {
            int e = mi * 16 + g * 4 + r;
            unsigned sx = (unsigned)((e & 7) << 4);
            #pragma unroll
            for (int a = 0; a < 4; ++a) {
                f32x2 t; t.x = a1[2 * a][r]; t.y = a1[2 * a + 1][r];
                t = t + bf2(pr[r][a]) + bf2(pc[r][a]) + b1v[a];  // pk_add x3
                f32x2 s = silu2(t);
                *reinterpret_cast<unsigned*>(
                    sw + e * 256 + ((a * 64 + q * 4) ^ sx)) = cvt_pk_bf16(s.x, s.y);
            }
        }
        #pragma unroll
        for (int r = 0; r < 4; ++r) { pr[r] = prn[r]; pc[r] = pcn[r]; }
    }
    // same-wave LDS RAW -> compiler lgkmcnt; no barrier

    // ---------------- layer 2: k=0..127 ----------------
    f32x4 acc2[4][8];
    #pragma unroll
    for (int mi = 0; mi < 4; ++mi)
        #pragma unroll
        for (int f = 0; f < 8; ++f) acc2[mi][f] = (f32x4)0.f;

    #pragma unroll
    for (int s = 0; s < 4; ++s) {
        s16x8 bf[8];
        #pragma unroll
        for (int f = 0; f < 8; ++f)
            bf[f] = *reinterpret_cast<const s16x8*>(
                W2p + ((s * 4 + g) * DIM + f * 16 + q) * 8);
        s16x8 av[4];
        #pragma unroll
        for (int mi = 0; mi < 4; ++mi) {
            int e = mi * 16 + q;
            av[mi] = *reinterpret_cast<const s16x8*>(
                sw + e * 256 + ((s * 64 + g * 16) ^ ((q & 7) << 4)));
        }
        #pragma unroll
        for (int mi = 0; mi < 4; ++mi)
            #pragma unroll
            for (int f = 0; f < 8; ++f) acc2[mi][f] = MFMA16(av[mi], bf[f], acc2[mi][f]);
    }

    // bias + silu (pairwise); attention dot via pk-fma; sigmoid*mask; pack msgs
    unsigned* smsg = reinterpret_cast<unsigned*>(sw);
    {
        f32x2 b2v[4], wav[4];
        #pragma unroll
        for (int a = 0; a < 4; ++a) {
            b2v[a] = *reinterpret_cast<const f32x2*>(bm2 + a * 32 + 2 * q);
            wav[a] = *reinterpret_cast<const f32x2*>(Wa  + a * 32 + 2 * q);
        }
        const float ba0 = ba[0];
        #pragma unroll
        for (int mi = 0; mi < 4; ++mi)
            #pragma unroll
            for (int r = 0; r < 4; ++r) {
                f32x2 pd = (f32x2)0.f;
                f32x2 vv[4];
                #pragma unroll
                for (int a = 0; a < 4; ++a) {
                    f32x2 t; t.x = acc2[mi][2 * a][r]; t.y = acc2[mi][2 * a + 1][r];
                    t = t + b2v[a];                  // pk_add
                    vv[a] = silu2(t);
                    pd = pd + vv[a] * wav[a];        // pk_fma
                }
                float p = pd.x + pd.y;
                p += __shfl_xor(p, 1);
                p += __shfl_xor(p, 2);
                p += __shfl_xor(p, 4);
                p += __shfl_xor(p, 8);
                int e = mi * 16 + g * 4 + r;
                float mk = __shfl(mskl, e);
                float sc = sigmoid_f(p + ba0) * mk;
                unsigned sx = ((unsigned)(e & 4)) << 2;
                #pragma unroll
                for (int a = 0; a < 4; ++a) {
                    f32x2 m = vv[a] * sc;            // pk_mul
                    smsg[e * 64 + ((a * 16 + q) ^ sx)] = cvt_pk_bf16(m.x, m.y);
                }
            }
    }

    // segmented run-reduction over the wave's 64 sorted edges (pk accumulate).
    {
        const int c = lane;
        f32x2 s = (f32x2)0.f;
        int prow = __builtin_amdgcn_readlane(rowl, 0);
        for (int jb = 0; jb < 64; jb += 8) {
            unsigned v[8];
            #pragma unroll
            for (int k = 0; k < 8; ++k)
                v[k] = smsg[(jb + k) * 64 + (c ^ (((jb + k) & 4) << 2))];
            #pragma unroll
            for (int k = 0; k < 8; ++k) {
                int rj = __builtin_amdgcn_readlane(rowl, jb + k);
                if (rj != prow) {                    // wave-uniform branch
                    float* dst = agg + (size_t)prow * DIM + (c >> 4) * 32 + 2 * (c & 15);
                    atomicAdd(dst, s.x);
                    atomicAdd(dst + 1, s.y);
                    s = (f32x2)0.f; prow = rj;
                }
                s = s + bf2(v[k]);                   // pk_add
            }
        }
        float* dst = agg + (size_t)prow * DIM + (c >> 4) * 32 + 2 * (c & 15);
        atomicAdd(dst, s.x);
        atomicAdd(dst + 1, s.y);
    }
}

// ---------------------------------------------------------------------------
// Node kernel: r12 structure (hoisted agg loads) + pairwise f32x2 epilogues.
// ---------------------------------------------------------------------------
__global__ __launch_bounds__(256, 4) void node_kernel(
    const unsigned short* __restrict__ h_bf,
    const float* __restrict__ agg,
    const float* __restrict__ h,
    const float* __restrict__ flags,
    const unsigned short* __restrict__ Wn1p,
    const float* __restrict__ bn1,
    const unsigned short* __restrict__ Wn2p,
    const float* __restrict__ bn2,
    float* __restrict__ out)
{
    __shared__ __align__(16) unsigned char s_u[4][4352];

    const int tid  = threadIdx.x;
    const int wv   = tid >> 6;
    const int lane = tid & 63;
    const int q    = lane & 15;
    const int g    = lane >> 4;
    const int n0w  = blockIdx.x * 64 + wv * 16;

    const int nq  = n0w + q;
    const int nqc = (nq < NN) ? nq : (NN - 1);

    // hoist ALL global loads: agg (8 x float4) + h_bf (4 x 16B)
    float4 au[4], avv[4];
    #pragma unroll
    for (int s = 0; s < 4; ++s) {
        const float4* pa = reinterpret_cast<const float4*>(
            agg + (size_t)nqc * DIM + s * 32 + g * 8);
        au[s] = pa[0]; avv[s] = pa[1];
    }
    s16x8 ah[4];
    #pragma unroll
    for (int s = 0; s < 4; ++s)
        ah[s] = *reinterpret_cast<const s16x8*>(
            h_bf + (size_t)nqc * DIM + s * 32 + g * 8);

    f32x4 acc[8];
    #pragma unroll
    for (int f = 0; f < 8; ++f) acc[f] = (f32x4)0.f;

    #pragma unroll
    for (int s = 0; s < 4; ++s) {
        #pragma unroll
        for (int f = 0; f < 8; ++f) {
            s16x8 b = *reinterpret_cast<const s16x8*>(
                Wn1p + ((s * 4 + g) * DIM + f * 16 + q) * 8);
            acc[f] = MFMA16(ah[s], b, acc[f]);
        }
    }
    #pragma unroll
    for (int s = 4; s < 8; ++s) {
        float4 u = au[s - 4], v = avv[s - 4];
        u32x4 pk;
        pk[0] = cvt_pk_bf16(u.x, u.y); pk[1] = cvt_pk_bf16(u.z, u.w);
        pk[2] = cvt_pk_bf16(v.x, v.y); pk[3] = cvt_pk_bf16(v.z, v.w);
        s16x8 a = __builtin_bit_cast(s16x8, pk);
        #pragma unroll
        for (int f = 0; f < 8; ++f) {
            s16x8 b = *reinterpret_cast<const s16x8*>(
                Wn1p + ((s * 4 + g) * DIM + f * 16 + q) * 8);
            acc[f] = MFMA16(a, b, acc[f]);
        }
    }

    unsigned char* sw = s_u[wv];
    {
        #pragma unroll
        for (int aa = 0; aa < 4; ++aa) {
            f32x2 bp = *reinterpret_cast<const f32x2*>(bn1 + aa * 32 + 2 * q);
            #pragma unroll
            for (int r = 0; r < 4; ++r) {
                f32x2 t; t.x = acc[2 * aa][r]; t.y = acc[2 * aa + 1][r];
                f32x2 s = silu2(t + bp);
                *reinterpret_cast<unsigned*>(
                    sw + (g * 4 + r) * 272 + aa * 64 + 4 * q) = cvt_pk_bf16(s.x, s.y);
            }
        }
    }

    f32x4 acc2[8];
    #pragma unroll
    for (int f = 0; f < 8; ++f) acc2[f] = (f32x4)0.f;

    #pragma unroll
    for (int s = 0; s < 4; ++s) {
        s16x8 a = *reinterpret_cast<const s16x8*>(sw + q * 272 + s * 64 + g * 16);
        #pragma unroll
        for (int f = 0; f < 8; ++f) {
            s16x8 b = *reinterpret_cast<const s16x8*>(
                Wn2p + ((s * 4 + g) * DIM + f * 16 + q) * 8);
            acc2[f] = MFMA16(a, b, acc2[f]);
        }
    }

    {
        #pragma unroll
        for (int r = 0; r < 4; ++r) {
            int n = n0w + 4 * g + r;
            if (n < NN) {
                float fl = flags[n];
                #pragma unroll
                for (int aa = 0; aa < 4; ++aa) {
                    f32x2 b2 = *reinterpret_cast<const f32x2*>(bn2 + aa * 32 + 2 * q);
                    size_t b = (size_t)n * DIM + aa * 32 + 2 * q;
                    f32x2 hv = *reinterpret_cast<const f32x2*>(h + b);
                    f32x2 t; t.x = acc2[2 * aa][r]; t.y = acc2[2 * aa + 1][r];
                    f32x2 o = (hv + t + b2) * fl;    // pk_add x2 + pk_mul
                    *reinterpret_cast<f32x2*>(out + b) = o;
                }
            }
        }
    }
}

extern "C" void kernel_launch(void* const* d_in, const int* in_sizes, int n_in,
                              void* d_out, int out_size, void* d_ws, size_t ws_size,
                              hipStream_t stream) {
    const float* h     = (const float*)d_in[0];
    const int*   ei    = (const int*)  d_in[1];
    const float* ea    = (const float*)d_in[2];
    const float* flags = (const float*)d_in[3];
    const float* emask = (const float*)d_in[4];
    const float* Wm1   = (const float*)d_in[5];
    const float* bm1   = (const float*)d_in[6];
    const float* Wm2   = (const float*)d_in[7];
    const float* bm2   = (const float*)d_in[8];
    const float* Wa    = (const float*)d_in[9];
    const float* ba    = (const float*)d_in[10];
    const float* Wn1   = (const float*)d_in[11];
    const float* bn1   = (const float*)d_in[12];
    const float* Wn2   = (const float*)d_in[13];
    const float* bn2   = (const float*)d_in[14];
    float* out = (float*)d_out;

    char* ws = (char*)d_ws;
    float*          agg   = (float*)         (ws);                 // 10,240,000
    unsigned short* h_bf  = (unsigned short*)(ws + 10240000);      //  5,120,000
    unsigned short* W1rp  = (unsigned short*)(ws + 15360000);      //     32,768
    unsigned short* W1cp  = (unsigned short*)(ws + 15392768);      //     32,768
    unsigned short* W1ep  = (unsigned short*)(ws + 15425536);      //      8,192
    unsigned short* W2p   = (unsigned short*)(ws + 15433728);      //     32,768
    unsigned short* Wn1p  = (unsigned short*)(ws + 15466496);      //     65,536
    unsigned short* Wn2p  = (unsigned short*)(ws + 15532032);      //     32,768
    int*            cnts  = (int*)           (ws + 15564800);      //     80,000
    int*            eidS  = (int*)           (ws + 15644800);      //  2,560,000
    unsigned short* rowS  = (unsigned short*)(ws + 18204800);      //  1,280,000
    unsigned*       P1r   = (unsigned*)      (ws + 19484800);      //  5,120,000
    unsigned*       P1c   = (unsigned*)      (ws + 24604800);      //  5,120,000
    const size_t WS_NEED = 29724800;

    const bool sorted = (ws_size >= WS_NEED);

    prep_all_kernel<<<5479, 256, 0, stream>>>(h, h_bf, Wm1, Wm2, Wn1, Wn2,
                                              W1rp, W1cp, W1ep, W2p, Wn1p, Wn2p,
                                              agg, cnts);

    if (sorted) {
        hist_proj_kernel<true><<<2813, 256, 0, stream>>>(
            ei, cnts, h_bf, W1rp, W1cp, P1r, P1c);
        scan_kernel<<<1, 1024, 0, stream>>>(cnts);
        scatter_kernel<<<(E_TOT + 255) / 256, 256, 0, stream>>>(ei, cnts, eidS, rowS);
        edge_kernel<true><<<E_TOT / 256, 256, 0, stream>>>(
            P1r, P1c, ei, eidS, rowS, ea, emask, W1ep, bm1, W2p, bm2, Wa, ba, agg);
    } else {
        hist_proj_kernel<false><<<313, 256, 0, stream>>>(
            ei, cnts, h_bf, W1rp, W1cp, P1r, P1c);
        edge_kernel<false><<<E_TOT / 256, 256, 0, stream>>>(
            P1r, P1c, ei, eidS, rowS, ea, emask, W1ep, bm1, W2p, bm2, Wa, ba, agg);
    }

    node_kernel<<<(NN + 63) / 64, 256, 0, stream>>>(h_bf, agg, h, flags,
                                                    Wn1p, bn1, Wn2p, bn2, out);
}

// Round 17
// 220.018 us; speedup vs baseline: 1.1913x; 1.0349x over previous
//
#include <hip/hip_runtime.h>
#include <math.h>

#define E_TOT   640000
#define NN      20000
#define DIM     128
#define EDGE_DIM 16

typedef float f32x4 __attribute__((ext_vector_type(4)));
typedef float f32x2 __attribute__((ext_vector_type(2)));
typedef short s16x8 __attribute__((ext_vector_type(8)));
typedef unsigned u32x4 __attribute__((ext_vector_type(4)));
typedef __bf16 bfx8 __attribute__((ext_vector_type(8)));

__device__ __forceinline__ unsigned short f2bf(float f) {
    unsigned u = __builtin_bit_cast(unsigned, f);
    u += 0x7fffu + ((u >> 16) & 1u);
    return (unsigned short)(u >> 16);
}
__device__ __forceinline__ unsigned cvt_pk_bf16(float lo, float hi) {
    unsigned r;
    asm("v_cvt_pk_bf16_f32 %0, %1, %2" : "=v"(r) : "v"(lo), "v"(hi));
    return r;
}
__device__ __forceinline__ float bf_lo(unsigned u) {
    return __builtin_bit_cast(float, u << 16);
}
__device__ __forceinline__ float bf_hi(unsigned u) {
    return __builtin_bit_cast(float, u & 0xffff0000u);
}
__device__ __forceinline__ f32x2 bf2(unsigned u) {
    f32x2 r; r.x = bf_lo(u); r.y = bf_hi(u); return r;
}
// fast transcendentals (no -ffast-math in harness): v_exp_f32 + v_rcp_f32.
__device__ __forceinline__ float fast_exp2(float x) {
    float r; asm("v_exp_f32 %0, %1" : "=v"(r) : "v"(x)); return r;
}
__device__ __forceinline__ float fast_rcp(float x) {
    float r; asm("v_rcp_f32 %0, %1" : "=v"(r) : "v"(x)); return r;
}
#define LOG2E 1.44269504f
__device__ __forceinline__ float sigmoid_f(float x) {
    return fast_rcp(1.0f + fast_exp2(-LOG2E * x));
}
// pairwise silu: muls/adds emit v_pk_*; exp/rcp stay scalar.
__device__ __forceinline__ f32x2 silu2(f32x2 x) {
    f32x2 nx = x * (-LOG2E);
    f32x2 e; e.x = fast_exp2(nx.x); e.y = fast_exp2(nx.y);
    f32x2 d = e + 1.0f;
    f32x2 rc; rc.x = fast_rcp(d.x); rc.y = fast_rcp(d.y);
    return x * rc;
}

#define MFMA16(a, b, c) __builtin_amdgcn_mfma_f32_16x16x32_bf16( \
    __builtin_bit_cast(bfx8, (a)), __builtin_bit_cast(bfx8, (b)), (c), 0, 0, 0)

// ---------------------------------------------------------------------------
// Weight pack (pair-permuted fragment-major):
// Wp[(sg*128 + f*16 + q)*8 + t] = W[k=sg*8+t][col], col=(f>>1)*32+2q+(f&1).
// ---------------------------------------------------------------------------
__device__ __forceinline__ void pack_w(const float* __restrict__ W,
                                       unsigned short* __restrict__ Wp,
                                       int K, int id) {
    int t   = id & 7;
    int pos = (id >> 3) & 127;
    int sg  = id >> 10;
    int qq = pos & 15, f = pos >> 4;
    int col = (f >> 1) * 32 + 2 * qq + (f & 1);
    int k = sg * 8 + t;
    Wp[id] = (k < K) ? f2bf(W[(size_t)k * DIM + col]) : (unsigned short)0;
}

// ---------------------------------------------------------------------------
// K1: hist (cnts pre-zeroed by tiny 80 KB memset) + weight packs + zero agg.
//  [0,2500): hist; [2500,2900): packs; [2900,5400): zero agg.
// ---------------------------------------------------------------------------
__global__ void hist_pack_kernel(const int* __restrict__ ei,
                                 int* __restrict__ cnts,
                                 const float* __restrict__ Wm1,
                                 const float* __restrict__ Wm2,
                                 const float* __restrict__ Wn1,
                                 const float* __restrict__ Wn2,
                                 unsigned short* __restrict__ W1rp,
                                 unsigned short* __restrict__ W1cp,
                                 unsigned short* __restrict__ W1ep,
                                 unsigned short* __restrict__ W2p,
                                 unsigned short* __restrict__ Wn1p,
                                 unsigned short* __restrict__ Wn2p,
                                 float* __restrict__ agg) {
    const int blk = blockIdx.x;
    const int tid = threadIdx.x;
    if (blk < 2500) {                       // hist
        int e = blk * 256 + tid;
        if (e < E_TOT) atomicAdd(&cnts[ei[e]], 1);
    } else if (blk < 2564) {                // W1rp: rows 0..127 of Wm1
        pack_w(Wm1, W1rp, 128, (blk - 2500) * 256 + tid);
    } else if (blk < 2628) {                // W1cp: rows 128..255
        pack_w(Wm1 + 128 * DIM, W1cp, 128, (blk - 2564) * 256 + tid);
    } else if (blk < 2644) {                // W1ep: rows 256..271, Kp=32
        pack_w(Wm1 + 256 * DIM, W1ep, 16, (blk - 2628) * 256 + tid);
    } else if (blk < 2708) {                // W2p: 128x128
        pack_w(Wm2, W2p, 128, (blk - 2644) * 256 + tid);
    } else if (blk < 2836) {                // Wn1p: 256x128
        pack_w(Wn1, Wn1p, 256, (blk - 2708) * 256 + tid);
    } else if (blk < 2900) {                // Wn2p: 128x128
        pack_w(Wn2, Wn2p, 128, (blk - 2836) * 256 + tid);
    } else {                                // zero agg (640000 f32x4)
        int i = (blk - 2900) * 256 + tid;
        reinterpret_cast<f32x4*>(agg)[i] = (f32x4)0.f;
    }
}

// ---------------------------------------------------------------------------
// K2: scan ∥ prep_h ∥ proj — one 1024-thread kernel so the 1-block scan no
// longer idles the GPU.
//  block 0: scan (counts -> exclusive prefix, in place);
//  [1,626): h -> h_bf (1024 f32x4 per block, 625*1024 = 640000 exactly);
//  [626,705): proj — P1r/P1c from RAW f32 h, converted with f2bf (software
//  RNE — BIT-IDENTICAL to prep_h's h_bf path; r16's cvt_pk here rounded
//  differently and breached the absmax threshold), 256 nodes per block.
// ---------------------------------------------------------------------------
template<bool SORTED>
__global__ __launch_bounds__(1024) void scan_preph_proj_kernel(
    int* __restrict__ counts,
    const float* __restrict__ h,
    unsigned short* __restrict__ h_bf,
    const unsigned short* __restrict__ W1rp,
    const unsigned short* __restrict__ W1cp,
    unsigned* __restrict__ P1r, unsigned* __restrict__ P1c)
{
    const int blk = blockIdx.x;
    const int tid = threadIdx.x;

    if (SORTED && blk == 0) {               // scan
        __shared__ int s[1024];
        const int CH = 20;
        int base = tid * CH;
        int loc[CH];
        int sum = 0;
        #pragma unroll
        for (int i = 0; i < CH; ++i) {
            int idx = base + i;
            loc[i] = (idx < NN) ? counts[idx] : 0;
            sum += loc[i];
        }
        s[tid] = sum;
        __syncthreads();
        for (int off = 1; off < 1024; off <<= 1) {
            int v = (tid >= off) ? s[tid - off] : 0;
            __syncthreads();
            s[tid] += v;
            __syncthreads();
        }
        int run = s[tid] - sum;
        #pragma unroll
        for (int i = 0; i < CH; ++i) {
            int idx = base + i;
            if (idx < NN) counts[idx] = run;
            run += loc[i];
        }
        return;
    }

    const int pb = SORTED ? blk : (blk + 1);   // shift so !SORTED skips scan
    if (pb < 626) {                          // h -> bf16
        int i = (pb - 1) * 1024 + tid;
        float4 v = reinterpret_cast<const float4*>(h)[i];
        unsigned short* d = h_bf + i * 4;
        d[0] = f2bf(v.x); d[1] = f2bf(v.y); d[2] = f2bf(v.z); d[3] = f2bf(v.w);
        return;
    }

    // proj (raw f32 h -> f2bf, bit-identical to h_bf; independent of prep_h)
    const int pblk = pb - 626;
    const int wv   = tid >> 6;               // 0..15
    const int lane = tid & 63;
    const int q    = lane & 15;
    const int g    = lane >> 4;
    const int n0w  = pblk * 256 + wv * 16;
    const int nq   = n0w + q;
    const int nqc  = (nq < NN) ? nq : (NN - 1);

    s16x8 av[4];
    #pragma unroll
    for (int s = 0; s < 4; ++s) {
        const float4* ph = reinterpret_cast<const float4*>(
            h + (size_t)nqc * DIM + s * 32 + g * 8);
        float4 u = ph[0], v = ph[1];
        unsigned short tmp[8];
        tmp[0] = f2bf(u.x); tmp[1] = f2bf(u.y); tmp[2] = f2bf(u.z); tmp[3] = f2bf(u.w);
        tmp[4] = f2bf(v.x); tmp[5] = f2bf(v.y); tmp[6] = f2bf(v.z); tmp[7] = f2bf(v.w);
        av[s] = *reinterpret_cast<const s16x8*>(tmp);
    }

    #pragma unroll
    for (int T = 0; T < 2; ++T) {
        const unsigned short* Wp = T ? W1cp : W1rp;
        unsigned* P = T ? P1c : P1r;
        f32x4 acc[8];
        #pragma unroll
        for (int f = 0; f < 8; ++f) acc[f] = (f32x4)0.f;
        #pragma unroll
        for (int s = 0; s < 4; ++s)
            #pragma unroll
            for (int f = 0; f < 8; ++f) {
                s16x8 b = *reinterpret_cast<const s16x8*>(
                    Wp + ((s * 4 + g) * DIM + f * 16 + q) * 8);
                acc[f] = MFMA16(av[s], b, acc[f]);
            }
        #pragma unroll
        for (int r = 0; r < 4; ++r) {
            int n = n0w + g * 4 + r;
            if (n < NN) {
                u32x4 o;
                #pragma unroll
                for (int a = 0; a < 4; ++a)
                    o[a] = cvt_pk_bf16(acc[2 * a][r], acc[2 * a + 1][r]);
                *reinterpret_cast<u32x4*>(P + (size_t)n * 64 + q * 4) = o;
            }
        }
    }
}

// ---------------------------------------------------------------------------
// K3: scatter (isolated — atomic-heavy; r14 showed fusing it regresses)
// ---------------------------------------------------------------------------
__global__ void scatter_kernel(const int* __restrict__ ei, int* __restrict__ cursor,
                               int* __restrict__ eidS, unsigned short* __restrict__ rowS) {
    int e = blockIdx.x * blockDim.x + threadIdx.x;
    if (e < E_TOT) {
        int r = ei[e];
        int p = atomicAdd(&cursor[r], 1);
        eidS[p] = e;
        rowS[p] = (unsigned short)r;
    }
}

// ---------------------------------------------------------------------------
// Edge kernel: r13 verbatim (best measured: 118.5 us). 4 waves/block, wave
// owns 64 edges x ALL 128 cols; factored layer 1 (P1r/P1c + ea-GEMM);
// pk-f32 epilogues; wave-private swizzled LDS; zero barriers; XCD swizzle;
// wave-uniform segmented run-reduction.
// ---------------------------------------------------------------------------
template<bool SORTED>
__global__ __launch_bounds__(256, 2) void edge_kernel(
    const unsigned* __restrict__ P1r,
    const unsigned* __restrict__ P1c,
    const int* __restrict__ ei,
    const int* __restrict__ eidS,
    const unsigned short* __restrict__ rowS,
    const float* __restrict__ ea,
    const float* __restrict__ emask,
    const unsigned short* __restrict__ W1ep,  // 32x128 packed (pair-permuted)
    const float* __restrict__ bm1,
    const unsigned short* __restrict__ W2p,   // 128x128 packed (pair-permuted)
    const float* __restrict__ bm2,
    const float* __restrict__ Wa, const float* __restrict__ ba,
    float* __restrict__ agg)
{
    __shared__ __align__(16) unsigned char s_u[4][16384];  // wave-private

    const int tid  = threadIdx.x;
    const int wv   = tid >> 6;
    const int lane = tid & 63;
    const int q    = lane & 15;
    const int g    = lane >> 4;

    // bijective XCD swizzle: contiguous sorted-edge tiles share one L2.
    const int nwg = gridDim.x;
    const int xcd = blockIdx.x & 7;
    const int loc = blockIdx.x >> 3;
    const int qq  = nwg >> 3, rr = nwg & 7;
    const int tile = (xcd < rr) ? (xcd * (qq + 1) + loc)
                                : (rr * (qq + 1) + (xcd - rr) * qq + loc);
    const int e0w = tile * 256 + wv * 64;

    // per-lane meta: lane l holds edge (e0w + l)
    const int   eidl = SORTED ? eidS[e0w + lane] : (e0w + lane);
    const int   rowl = SORTED ? (int)rowS[e0w + lane] : ei[eidl];
    const int   coll = ei[E_TOT + eidl];
    const float mskl = emask[eidl];

    const u32x4* P1r4 = reinterpret_cast<const u32x4*>(P1r);
    const u32x4* P1c4 = reinterpret_cast<const u32x4*>(P1c);

    // ea A-fragments for all mi (lane (q,g) covers edge mi*16+q, k=g*8..+8)
    s16x8 eav[4];
    #pragma unroll
    for (int mi = 0; mi < 4; ++mi) {
        int eid = __shfl(eidl, mi * 16 + q);
        eav[mi] = (s16x8)0;
        if (g < 2) {
            const float4* pe = reinterpret_cast<const float4*>(
                ea + (size_t)eid * EDGE_DIM + g * 8);
            float4 u = pe[0], v = pe[1];
            u32x4 pk;
            pk[0] = cvt_pk_bf16(u.x, u.y); pk[1] = cvt_pk_bf16(u.z, u.w);
            pk[2] = cvt_pk_bf16(v.x, v.y); pk[3] = cvt_pk_bf16(v.z, v.w);
            eav[mi] = __builtin_bit_cast(s16x8, pk);
        }
    }

    // W1e B-fragments (Kp=32 -> single s-step, sg=g)
    s16x8 w1e[8];
    #pragma unroll
    for (int f = 0; f < 8; ++f)
        w1e[f] = *reinterpret_cast<const s16x8*>(
            W1ep + ((size_t)g * DIM + f * 16 + q) * 8);

    f32x2 b1v[4];
    #pragma unroll
    for (int a = 0; a < 4; ++a)
        b1v[a] = *reinterpret_cast<const f32x2*>(bm1 + a * 32 + 2 * q);

    unsigned char* sw = s_u[wv];

    // prefetch P for mi=0 (epilogue lane (q,g) handles edges mi*16+g*4+r)
    u32x4 pr[4], pc[4];
    #pragma unroll
    for (int r = 0; r < 4; ++r) {
        int e = g * 4 + r;
        pr[r] = P1r4[(size_t)__shfl(rowl, e) * 16 + q];
        pc[r] = P1c4[(size_t)__shfl(coll, e) * 16 + q];
    }

    // ---------------- layer 1 (factored), per-mi ----------------
    #pragma unroll
    for (int mi = 0; mi < 4; ++mi) {
        f32x4 a1[8];
        #pragma unroll
        for (int f = 0; f < 8; ++f) a1[f] = (f32x4)0.f;
        #pragma unroll
        for (int f = 0; f < 8; ++f) a1[f] = MFMA16(eav[mi], w1e[f], a1[f]);

        // prefetch next mi's P-rows while this epilogue runs
        u32x4 prn[4], pcn[4];
        if (mi < 3) {
            #pragma unroll
            for (int r = 0; r < 4; ++r) {
                int e = (mi + 1) * 16 + g * 4 + r;
                prn[r] = P1r4[(size_t)__shfl(rowl, e) * 16 + q];
                pcn[r] = P1c4[(size_t)__shfl(coll, e) * 16 + q];
            }
        }

        #pragma unroll
        for (int r = 0; r < 4; ++r) {
            int e = mi * 16 + g * 4 + r;
            unsigned sx = (unsigned)((e & 7) << 4);
            #pragma unroll
            for (int a = 0; a < 4; ++a) {
                f32x2 t; t.x = a1[2 * a][r]; t.y = a1[2 * a + 1][r];
                t = t + bf2(pr[r][a]) + bf2(pc[r][a]) + b1v[a];  // pk_add x3
                f32x2 s = silu2(t);
                *reinterpret_cast<unsigned*>(
                    sw + e * 256 + ((a * 64 + q * 4) ^ sx)) = cvt_pk_bf16(s.x, s.y);
            }
        }
        #pragma unroll
        for (int r = 0; r < 4; ++r) { pr[r] = prn[r]; pc[r] = pcn[r]; }
    }
    // same-wave LDS RAW -> compiler lgkmcnt; no barrier

    // ---------------- layer 2: k=0..127 ----------------
    f32x4 acc2[4][8];
    #pragma unroll
    for (int mi = 0; mi < 4; ++mi)
        #pragma unroll
        for (int f = 0; f < 8; ++f) acc2[mi][f] = (f32x4)0.f;

    #pragma unroll
    for (int s = 0; s < 4; ++s) {
        s16x8 bf[8];
        #pragma unroll
        for (int f = 0; f < 8; ++f)
            bf[f] = *reinterpret_cast<const s16x8*>(
                W2p + ((s * 4 + g) * DIM + f * 16 + q) * 8);
        s16x8 av[4];
        #pragma unroll
        for (int mi = 0; mi < 4; ++mi) {
            int e = mi * 16 + q;
            av[mi] = *reinterpret_cast<const s16x8*>(
                sw + e * 256 + ((s * 64 + g * 16) ^ ((q & 7) << 4)));
        }
        #pragma unroll
        for (int mi = 0; mi < 4; ++mi)
            #pragma unroll
            for (int f = 0; f < 8; ++f) acc2[mi][f] = MFMA16(av[mi], bf[f], acc2[mi][f]);
    }

    // bias + silu (pairwise); attention dot via pk-fma; sigmoid*mask; pack msgs
    unsigned* smsg = reinterpret_cast<unsigned*>(sw);
    {
        f32x2 b2v[4], wav[4];
        #pragma unroll
        for (int a = 0; a < 4; ++a) {
            b2v[a] = *reinterpret_cast<const f32x2*>(bm2 + a * 32 + 2 * q);
            wav[a] = *reinterpret_cast<const f32x2*>(Wa  + a * 32 + 2 * q);
        }
        const float ba0 = ba[0];
        #pragma unroll
        for (int mi = 0; mi < 4; ++mi)
            #pragma unroll
            for (int r = 0; r < 4; ++r) {
                f32x2 pd = (f32x2)0.f;
                f32x2 vv[4];
                #pragma unroll
                for (int a = 0; a < 4; ++a) {
                    f32x2 t; t.x = acc2[mi][2 * a][r]; t.y = acc2[mi][2 * a + 1][r];
                    t = t + b2v[a];                  // pk_add
                    vv[a] = silu2(t);
                    pd = pd + vv[a] * wav[a];        // pk_fma
                }
                float p = pd.x + pd.y;
                p += __shfl_xor(p, 1);
                p += __shfl_xor(p, 2);
                p += __shfl_xor(p, 4);
                p += __shfl_xor(p, 8);
                int e = mi * 16 + g * 4 + r;
                float mk = __shfl(mskl, e);
                float sc = sigmoid_f(p + ba0) * mk;
                unsigned sx = ((unsigned)(e & 4)) << 2;
                #pragma unroll
                for (int a = 0; a < 4; ++a) {
                    f32x2 m = vv[a] * sc;            // pk_mul
                    smsg[e * 64 + ((a * 16 + q) ^ sx)] = cvt_pk_bf16(m.x, m.y);
                }
            }
    }

    // segmented run-reduction over the wave's 64 sorted edges (pk accumulate).
    {
        const int c = lane;
        f32x2 s = (f32x2)0.f;
        int prow = __builtin_amdgcn_readlane(rowl, 0);
        for (int jb = 0; jb < 64; jb += 8) {
            unsigned v[8];
            #pragma unroll
            for (int k = 0; k < 8; ++k)
                v[k] = smsg[(jb + k) * 64 + (c ^ (((jb + k) & 4) << 2))];
            #pragma unroll
            for (int k = 0; k < 8; ++k) {
                int rj = __builtin_amdgcn_readlane(rowl, jb + k);
                if (rj != prow) {                    // wave-uniform branch
                    float* dst = agg + (size_t)prow * DIM + (c >> 4) * 32 + 2 * (c & 15);
                    atomicAdd(dst, s.x);
                    atomicAdd(dst + 1, s.y);
                    s = (f32x2)0.f; prow = rj;
                }
                s = s + bf2(v[k]);                   // pk_add
            }
        }
        float* dst = agg + (size_t)prow * DIM + (c >> 4) * 32 + 2 * (c & 15);
        atomicAdd(dst, s.x);
        atomicAdd(dst + 1, s.y);
    }
}

// ---------------------------------------------------------------------------
// Node kernel: r13 verbatim (hoisted agg loads + pairwise f32x2 epilogues).
// ---------------------------------------------------------------------------
__global__ __launch_bounds__(256, 4) void node_kernel(
    const unsigned short* __restrict__ h_bf,
    const float* __restrict__ agg,
    const float* __restrict__ h,
    const float* __restrict__ flags,
    const unsigned short* __restrict__ Wn1p,
    const float* __restrict__ bn1,
    const unsigned short* __restrict__ Wn2p,
    const float* __restrict__ bn2,
    float* __restrict__ out)
{
    __shared__ __align__(16) unsigned char s_u[4][4352];

    const int tid  = threadIdx.x;
    const int wv   = tid >> 6;
    const int lane = tid & 63;
    const int q    = lane & 15;
    const int g    = lane >> 4;
    const int n0w  = blockIdx.x * 64 + wv * 16;

    const int nq  = n0w + q;
    const int nqc = (nq < NN) ? nq : (NN - 1);

    // hoist ALL global loads: agg (8 x float4) + h_bf (4 x 16B)
    float4 au[4], avv[4];
    #pragma unroll
    for (int s = 0; s < 4; ++s) {
        const float4* pa = reinterpret_cast<const float4*>(
            agg + (size_t)nqc * DIM + s * 32 + g * 8);
        au[s] = pa[0]; avv[s] = pa[1];
    }
    s16x8 ah[4];
    #pragma unroll
    for (int s = 0; s < 4; ++s)
        ah[s] = *reinterpret_cast<const s16x8*>(
            h_bf + (size_t)nqc * DIM + s * 32 + g * 8);

    f32x4 acc[8];
    #pragma unroll
    for (int f = 0; f < 8; ++f) acc[f] = (f32x4)0.f;

    #pragma unroll
    for (int s = 0; s < 4; ++s) {
        #pragma unroll
        for (int f = 0; f < 8; ++f) {
            s16x8 b = *reinterpret_cast<const s16x8*>(
                Wn1p + ((s * 4 + g) * DIM + f * 16 + q) * 8);
            acc[f] = MFMA16(ah[s], b, acc[f]);
        }
    }
    #pragma unroll
    for (int s = 4; s < 8; ++s) {
        float4 u = au[s - 4], v = avv[s - 4];
        u32x4 pk;
        pk[0] = cvt_pk_bf16(u.x, u.y); pk[1] = cvt_pk_bf16(u.z, u.w);
        pk[2] = cvt_pk_bf16(v.x, v.y); pk[3] = cvt_pk_bf16(v.z, v.w);
        s16x8 a = __builtin_bit_cast(s16x8, pk);
        #pragma unroll
        for (int f = 0; f < 8; ++f) {
            s16x8 b = *reinterpret_cast<const s16x8*>(
                Wn1p + ((s * 4 + g) * DIM + f * 16 + q) * 8);
            acc[f] = MFMA16(a, b, acc[f]);
        }
    }

    unsigned char* sw = s_u[wv];
    {
        #pragma unroll
        for (int aa = 0; aa < 4; ++aa) {
            f32x2 bp = *reinterpret_cast<const f32x2*>(bn1 + aa * 32 + 2 * q);
            #pragma unroll
            for (int r = 0; r < 4; ++r) {
                f32x2 t; t.x = acc[2 * aa][r]; t.y = acc[2 * aa + 1][r];
                f32x2 s = silu2(t + bp);
                *reinterpret_cast<unsigned*>(
                    sw + (g * 4 + r) * 272 + aa * 64 + 4 * q) = cvt_pk_bf16(s.x, s.y);
            }
        }
    }

    f32x4 acc2[8];
    #pragma unroll
    for (int f = 0; f < 8; ++f) acc2[f] = (f32x4)0.f;

    #pragma unroll
    for (int s = 0; s < 4; ++s) {
        s16x8 a = *reinterpret_cast<const s16x8*>(sw + q * 272 + s * 64 + g * 16);
        #pragma unroll
        for (int f = 0; f < 8; ++f) {
            s16x8 b = *reinterpret_cast<const s16x8*>(
                Wn2p + ((s * 4 + g) * DIM + f * 16 + q) * 8);
            acc2[f] = MFMA16(a, b, acc2[f]);
        }
    }

    {
        #pragma unroll
        for (int r = 0; r < 4; ++r) {
            int n = n0w + 4 * g + r;
            if (n < NN) {
                float fl = flags[n];
                #pragma unroll
                for (int aa = 0; aa < 4; ++aa) {
                    f32x2 b2 = *reinterpret_cast<const f32x2*>(bn2 + aa * 32 + 2 * q);
                    size_t b = (size_t)n * DIM + aa * 32 + 2 * q;
                    f32x2 hv = *reinterpret_cast<const f32x2*>(h + b);
                    f32x2 t; t.x = acc2[2 * aa][r]; t.y = acc2[2 * aa + 1][r];
                    f32x2 o = (hv + t + b2) * fl;    // pk_add x2 + pk_mul
                    *reinterpret_cast<f32x2*>(out + b) = o;
                }
            }
        }
    }
}

extern "C" void kernel_launch(void* const* d_in, const int* in_sizes, int n_in,
                              void* d_out, int out_size, void* d_ws, size_t ws_size,
                              hipStream_t stream) {
    const float* h     = (const float*)d_in[0];
    const int*   ei    = (const int*)  d_in[1];
    const float* ea    = (const float*)d_in[2];
    const float* flags = (const float*)d_in[3];
    const float* emask = (const float*)d_in[4];
    const float* Wm1   = (const float*)d_in[5];
    const float* bm1   = (const float*)d_in[6];
    const float* Wm2   = (const float*)d_in[7];
    const float* bm2   = (const float*)d_in[8];
    const float* Wa    = (const float*)d_in[9];
    const float* ba    = (const float*)d_in[10];
    const float* Wn1   = (const float*)d_in[11];
    const float* bn1   = (const float*)d_in[12];
    const float* Wn2   = (const float*)d_in[13];
    const float* bn2   = (const float*)d_in[14];
    float* out = (float*)d_out;

    char* ws = (char*)d_ws;
    float*          agg   = (float*)         (ws);                 // 10,240,000
    unsigned short* h_bf  = (unsigned short*)(ws + 10240000);      //  5,120,000
    unsigned short* W1rp  = (unsigned short*)(ws + 15360000);      //     32,768
    unsigned short* W1cp  = (unsigned short*)(ws + 15392768);      //     32,768
    unsigned short* W1ep  = (unsigned short*)(ws + 15425536);      //      8,192
    unsigned short* W2p   = (unsigned short*)(ws + 15433728);      //     32,768
    unsigned short* Wn1p  = (unsigned short*)(ws + 15466496);      //     65,536
    unsigned short* Wn2p  = (unsigned short*)(ws + 15532032);      //     32,768
    int*            cnts  = (int*)           (ws + 15564800);      //     80,000
    int*            eidS  = (int*)           (ws + 15644800);      //  2,560,000
    unsigned short* rowS  = (unsigned short*)(ws + 18204800);      //  1,280,000
    unsigned*       P1r   = (unsigned*)      (ws + 19484800);      //  5,120,000
    unsigned*       P1c   = (unsigned*)      (ws + 24604800);      //  5,120,000
    const size_t WS_NEED = 29724800;

    const bool sorted = (ws_size >= WS_NEED);

    hipMemsetAsync(cnts, 0, NN * sizeof(int), stream);   // tiny (80 KB)
    hist_pack_kernel<<<5400, 256, 0, stream>>>(
        ei, cnts, Wm1, Wm2, Wn1, Wn2,
        W1rp, W1cp, W1ep, W2p, Wn1p, Wn2p, agg);

    if (sorted) {
        scan_preph_proj_kernel<true><<<705, 1024, 0, stream>>>(
            cnts, h, h_bf, W1rp, W1cp, P1r, P1c);
        scatter_kernel<<<(E_TOT + 255) / 256, 256, 0, stream>>>(ei, cnts, eidS, rowS);
        edge_kernel<true><<<E_TOT / 256, 256, 0, stream>>>(
            P1r, P1c, ei, eidS, rowS, ea, emask, W1ep, bm1, W2p, bm2, Wa, ba, agg);
    } else {
        scan_preph_proj_kernel<false><<<704, 1024, 0, stream>>>(
            cnts, h, h_bf, W1rp, W1cp, P1r, P1c);
        edge_kernel<false><<<E_TOT / 256, 256, 0, stream>>>(
            P1r, P1c, ei, eidS, rowS, ea, emask, W1ep, bm1, W2p, bm2, Wa, ba, agg);
    }

    node_kernel<<<(NN + 63) / 64, 256, 0, stream>>>(h_bf, agg, h, flags,
                                                    Wn1p, bn1, Wn2p, bn2, out);
}